// Round 2
// baseline (479.551 us; speedup 1.0000x reference)
//
#include <hip/hip_runtime.h>
#include <hip/hip_bf16.h>
#include <stdint.h>

// ---------------------------------------------------------------------------
// RegionLayer: 64 regions (8x8 grid of 8x8 patches), per-region:
//   hh = relu(BN(x));  y = conv3x3(hh, w[net]) + b[net] + x
// net = gj*(gi+1).  B=16, C=256, H=W=64, fp32 in/out; conv via bf16 MFMA.
// d_ws: [0, 75497472) bf16 weights [net][tap][co][ci]
//       [75497472, +33554432) bf16 hh [reg][b][px][c]
// Round-2 changes:
//  * conv: B-fragments loaded dwordx4 direct global->reg (no LDS, no
//    per-tap barrier); A staged ONCE (64KB, swizzled) -> 1 barrier pair
//    per block, 1152 MFMAs between barriers; halo rows read a zeroed row.
//  * wtrans/bnrelu: LDS transpose with 16B/lane coalesced global writes.
// ---------------------------------------------------------------------------

typedef __attribute__((ext_vector_type(8))) short bf16x8;
typedef __attribute__((ext_vector_type(4))) float f32x4;

typedef const __attribute__((address_space(1))) unsigned int gu32;
typedef __attribute__((address_space(3))) unsigned int lu32;

__device__ __forceinline__ void g2l16(const void* g, void* l) {
  __builtin_amdgcn_global_load_lds((gu32*)g, (lu32*)l, 16, 0, 0);
}

__device__ __forceinline__ unsigned short f2bf(float f) {
  union { __hip_bfloat16 h; unsigned short u; } cv;
  cv.h = __float2bfloat16(f);
  return cv.u;
}

// ---------------------------------------------------------------------------
// Kernel 1: conv_w [net][co][ci][tap] fp32 -> wb [net][tap][co][ci] bf16.
// Block = (co8 grp of 8 co, net). Phase 1: thread reads 18 contiguous floats
// (ci pair, all 9 taps) -> packed b32 LDS writes (2-way, free).
// Phase 2: ds_read_b128 + dwordx4 global writes, fully coalesced.
// ---------------------------------------------------------------------------
__global__ void wtrans_kernel(const float* __restrict__ w,
                              __hip_bfloat16* __restrict__ wb) {
  const int co8 = blockIdx.x;   // 0..31
  const int net = blockIdx.y;   // 0..63
  const int tid = threadIdx.x;
  __shared__ __align__(16) unsigned short t[9 * 8 * 256];  // 36864 B

  const int cip = tid & 127;  // ci-pair index
  const int ch  = tid >> 7;   // co half
  const int ci0 = cip * 2;

#pragma unroll
  for (int cl = 0; cl < 4; ++cl) {
    const int col = ch * 4 + cl;  // co_local 0..7
    const int co = co8 * 8 + col;
    const float* src = w + ((size_t)(net * 256 + co) * 256 + ci0) * 9;
    float a[18];
#pragma unroll
    for (int i = 0; i < 18; ++i) a[i] = src[i];
#pragma unroll
    for (int tap = 0; tap < 9; ++tap) {
      unsigned int pk = (unsigned)f2bf(a[tap]) | ((unsigned)f2bf(a[tap + 9]) << 16);
      *(unsigned int*)&t[tap * 2048 + col * 256 + ci0] = pk;
    }
  }
  __syncthreads();

  __hip_bfloat16* base = wb + (size_t)net * 589824;
#pragma unroll
  for (int k = 0; k < 9; ++k) {
    int ck = k * 256 + tid;            // 0..2303 16B-chunks
    int tap = ck >> 8;
    int col = (ck >> 5) & 7;
    int cr = ck & 31;
    bf16x8 v = *(const bf16x8*)&t[tap * 2048 + col * 256 + cr * 8];
    unsigned short* dst = (unsigned short*)base +
        ((size_t)tap * 256 + co8 * 8 + col) * 256 + cr * 8;
    *(bf16x8*)dst = v;
  }
}

// ---------------------------------------------------------------------------
// Kernel 2: BN+ReLU + NCHW -> per-region NHWC bf16, block = (reg, b).
// Phase 1: coalesced-ish fp32 reads (8x32B segs/instr), bf16 pack,
// ds_write_b128 at chunk-swizzled slot. Phase 2: ds_read_b128 (chunks
// permuted per row) + 16B/lane coalesced global writes.
// ---------------------------------------------------------------------------
__global__ void bnrelu_kernel(const float* __restrict__ x,
                              const float* __restrict__ gamma,
                              const float* __restrict__ beta,
                              const float* __restrict__ mean,
                              const float* __restrict__ var,
                              __hip_bfloat16* __restrict__ hh) {
  const int blk = blockIdx.x;
  const int reg = blk >> 4, b = blk & 15;
  const int gi = reg >> 3, gj = reg & 7;
  const int net = gj * (gi + 1);
  const int tid = threadIdx.x;

  __shared__ float sc[256], sh[256];
  __shared__ __align__(16) unsigned short tile[64 * 256];  // 32 KB

  {
    float g = gamma[net * 256 + tid];
    float bt = beta[net * 256 + tid];
    float m = mean[net * 256 + tid];
    float v = var[net * 256 + tid];
    float s = g * rsqrtf(v + 1e-5f);
    sc[tid] = s;
    sh[tid] = bt - m * s;
  }
  __syncthreads();

  const float* xb = x + (size_t)b * 1048576 + (gi * 8) * 64 + gj * 8;
  const int px = tid & 63, cw = tid >> 6;
  const int yy = px >> 3, xx = px & 7;

#pragma unroll
  for (int j = 0; j < 8; ++j) {
    const int chunk = cw * 8 + j;  // logical 8-channel chunk 0..31
    const int c0 = chunk * 8;
    bf16x8 v;
#pragma unroll
    for (int e = 0; e < 8; ++e) {
      int c = c0 + e;
      float tv = xb[(size_t)c * 4096 + yy * 64 + xx];
      tv = fmaxf(tv * sc[c] + sh[c], 0.f);
      v[e] = (short)f2bf(tv);
    }
    int phys = (chunk + px) & 31;
    *(bf16x8*)&tile[px * 256 + phys * 8] = v;
  }
  __syncthreads();

  unsigned short* hb = (unsigned short*)(hh + (size_t)(reg * 16 + b) * 16384);
#pragma unroll
  for (int k = 0; k < 8; ++k) {
    int ck = k * 256 + tid;
    int p = ck >> 5, cl = ck & 31;
    int phys = (cl + p) & 31;
    bf16x8 v = *(const bf16x8*)&tile[p * 256 + phys * 8];
    *(bf16x8*)(hb + p * 256 + cl * 8) = v;
  }
}

// ---------------------------------------------------------------------------
// Kernel 3: implicit-GEMM conv via mfma_f32_16x16x32_bf16.
// Block = (r, mt, nt): 128 M-rows (2 batches x 64 px) x 128 out-ch.
// A (128row x 256ch bf16 = 64KB) staged ONCE via global_load_lds(16B) with
// 8-chunk rotate swizzle; row 128 zeroed for conv halo. B fragments loaded
// directly global->reg as dwordx4 (16 rows x 64B contiguous per wave-instr).
// Single barrier pair; 4cc x 9tap x 32 MFMA with compiler-pipelined vmcnt.
// ---------------------------------------------------------------------------
__global__ __launch_bounds__(256, 2) void conv_kernel(
    const __hip_bfloat16* __restrict__ hh,
    const __hip_bfloat16* __restrict__ wb,
    const float* __restrict__ xin,
    const float* __restrict__ cbias,
    float* __restrict__ outp) {
  __shared__ __align__(16) char sA[66048];  // 129 rows x 512B

  const int bx = blockIdx.x;
  const int r = bx >> 4;
  const int mt = bx & 7;
  const int nt = (bx >> 3) & 1;
  const int gi = r >> 3, gj = r & 7;
  const int net = gj * (gi + 1);

  const int tid = threadIdx.x;
  const int lane = tid & 63;
  const int wv = tid >> 6;
  const int wm = (wv & 1) * 64;
  const int wn = (wv >> 1) * 64;
  const int ln = lane & 15;
  const int q = lane >> 4;

  const __hip_bfloat16* Aslab = hh + (size_t)(r * 16 + mt * 2) * (64 * 256);

  // Stage A: 128 rows x 32 chunks(16B), phys chunk = oct*8 + ((log&7)+row)&7.
#pragma unroll
  for (int i = 0; i < 16; ++i) {
    int s = i * 256 + tid;
    int row = s >> 5, sp = s & 31;
    int cl = (sp & 24) | (((sp & 7) - row) & 7);  // logical chunk
    g2l16(Aslab + (size_t)row * 256 + cl * 8, sA + s * 16);
  }
  if (tid < 32) *(f32x4*)(sA + 65536 + tid * 16) = (f32x4){0.f, 0.f, 0.f, 0.f};
  __syncthreads();

  // B per-lane base: row = nt*128 + wn + nf*16 + ln, k-offset q*8.
  const unsigned short* Bl = (const unsigned short*)wb +
      (size_t)net * 589824 + (size_t)(nt * 128 + wn + ln) * 256 + q * 8;

  int bl[4], py[4], pxr[4];
#pragma unroll
  for (int mf = 0; mf < 4; ++mf) {
    int m = wm + mf * 16 + ln;
    bl[mf] = m >> 6;
    py[mf] = (m >> 3) & 7;
    pxr[mf] = m & 7;
  }

  f32x4 acc[4][4];
#pragma unroll
  for (int mf = 0; mf < 4; ++mf)
#pragma unroll
    for (int nf = 0; nf < 4; ++nf)
      acc[mf][nf] = (f32x4){0.f, 0.f, 0.f, 0.f};

#pragma unroll 1
  for (int cc = 0; cc < 4; ++cc) {
#pragma unroll
    for (int tap = 0; tap < 9; ++tap) {
      const int dy = tap / 3 - 1, dx = tap % 3 - 1;
      // B fragments: direct global->reg, coalesced 16 rows x 64B.
      bf16x8 bfr[4][2];
#pragma unroll
      for (int nf = 0; nf < 4; ++nf)
#pragma unroll
        for (int kk = 0; kk < 2; ++kk)
          bfr[nf][kk] = *(const bf16x8*)(Bl + (size_t)tap * 65536 +
                                         nf * 4096 + cc * 64 + kk * 32);
      // A rows (halo -> zero row 128)
      int arow[4];
#pragma unroll
      for (int mf = 0; mf < 4; ++mf) {
        int sy = py[mf] + dy, sx = pxr[mf] + dx;
        bool v = ((unsigned)sy < 8u) & ((unsigned)sx < 8u);
        arow[mf] = v ? (bl[mf] * 64 + sy * 8 + sx) : 128;
      }
#pragma unroll
      for (int kk = 0; kk < 2; ++kk) {
        bf16x8 afr[4];
#pragma unroll
        for (int mf = 0; mf < 4; ++mf) {
          int row = arow[mf];
          int phys = cc * 8 + ((kk * 4 + q + row) & 7);
          afr[mf] = *(const bf16x8*)(sA + row * 512 + phys * 16);
        }
#pragma unroll
        for (int mf = 0; mf < 4; ++mf)
#pragma unroll
          for (int nf = 0; nf < 4; ++nf)
            acc[mf][nf] = __builtin_amdgcn_mfma_f32_16x16x32_bf16(
                afr[mf], bfr[nf][kk], acc[mf][nf], 0, 0, 0);
      }
    }
  }

  // Epilogue: D col = lane&15 (n), row = q*4+reg (m): 4 consecutive x-pixels
  // per lane -> aligned float4 residual load + store.
  const int nbase = nt * 128 + wn;
#pragma unroll
  for (int nf = 0; nf < 4; ++nf) {
    const int n = nbase + nf * 16 + ln;
    const float cb = cbias[net * 256 + n];
#pragma unroll
    for (int mf = 0; mf < 4; ++mf) {
      int mloc = wm + mf * 16 + q * 4;
      int b = mt * 2 + (mloc >> 6);
      int px = mloc & 63;
      int yy = px >> 3, x0 = px & 7;
      size_t off =
          (((size_t)b * 256 + n) * 64 + (gi * 8 + yy)) * 64 + (gj * 8 + x0);
      f32x4 res = *(const f32x4*)(xin + off);
      f32x4 o = acc[mf][nf];
      o = o + res;
      o = o + cb;
      *(f32x4*)(outp + off) = o;
    }
  }
}

// ---------------------------------------------------------------------------
extern "C" void kernel_launch(void* const* d_in, const int* in_sizes, int n_in,
                              void* d_out, int out_size, void* d_ws,
                              size_t ws_size, hipStream_t stream) {
  const float* x      = (const float*)d_in[0];
  const float* gamma  = (const float*)d_in[1];
  const float* beta   = (const float*)d_in[2];
  const float* mean   = (const float*)d_in[3];
  const float* var    = (const float*)d_in[4];
  const float* conv_w = (const float*)d_in[5];
  const float* conv_b = (const float*)d_in[6];
  float* out = (float*)d_out;

  __hip_bfloat16* wb = (__hip_bfloat16*)d_ws;                      // 75497472 B
  __hip_bfloat16* hh = (__hip_bfloat16*)((char*)d_ws + 75497472);  // 33554432 B

  wtrans_kernel<<<dim3(32, 64), 256, 0, stream>>>(conv_w, wb);
  bnrelu_kernel<<<1024, 256, 0, stream>>>(x, gamma, beta, mean, var, hh);
  conv_kernel<<<1024, 256, 0, stream>>>(hh, wb, x, conv_b, out);
}

// Round 3
// 443.369 us; speedup vs baseline: 1.0816x; 1.0816x over previous
//
#include <hip/hip_runtime.h>
#include <hip/hip_bf16.h>
#include <stdint.h>

// ---------------------------------------------------------------------------
// RegionLayer: 64 regions (8x8 grid of 8x8 patches), per-region:
//   hh = relu(BN(x));  y = conv3x3(hh, w[net]) + b[net] + x
// net = gj*(gi+1).  B=16, C=256, H=W=64, fp32 in/out; conv via bf16 MFMA.
// d_ws: [0, 75497472) bf16 weights [net][tap][co][ci]
//       [75497472, +33554432) bf16 hh [reg][b][px][c]
// Round-3: conv rebuilt around 128x128 wave tile (256 acc VGPR, 1 wave/SIMD,
// grid=256=1 block/CU) -> LDS bytes/MFMA halved vs r1 => MFMA-bound.
// B LDS-staged (16KB K32 chunks, double-buffered, prefetch after barrier).
// wtrans rebuilt: g2l16 raw staging + LDS gather (reads were 80+ us of
// stride-72B scalar transactions in r2).
// ---------------------------------------------------------------------------

typedef __attribute__((ext_vector_type(8))) short bf16x8;
typedef __attribute__((ext_vector_type(4))) float f32x4;

typedef const __attribute__((address_space(1))) unsigned int gu32;
typedef __attribute__((address_space(3))) unsigned int lu32;

__device__ __forceinline__ void g2l16(const void* g, void* l) {
  __builtin_amdgcn_global_load_lds((gu32*)g, (lu32*)l, 16, 0, 0);
}

__device__ __forceinline__ unsigned short f2bf(float f) {
  union { __hip_bfloat16 h; unsigned short u; } cv;
  cv.h = __float2bfloat16(f);
  return cv.u;
}

// ---------------------------------------------------------------------------
// Kernel 1: conv_w [net][co][ci][tap] fp32 -> wb [net][tap][co][ci] bf16.
// Block = (co-group of 4, net). Phase 1: g2l16 the 36864B fp32 slab into LDS
// raw (coalesced, zero VALU). Phase 2: per 16B-out-chunk gather 8 stride-9
// dwords from LDS (tap-fastest chunk order -> near-consecutive banks),
// convert, 16B/lane global store.
// ---------------------------------------------------------------------------
__global__ void wtrans_kernel(const float* __restrict__ w,
                              __hip_bfloat16* __restrict__ wb) {
  const int cog = blockIdx.x;   // 0..63 (4 co each)
  const int net = blockIdx.y;   // 0..63
  const int tid = threadIdx.x;
  __shared__ __align__(16) float wsm[9216];  // 4 co x 256 ci x 9 taps fp32

  const float* src = w + ((size_t)net * 256 + cog * 4) * 2304;
#pragma unroll
  for (int p = 0; p < 9; ++p) {
    int s = p * 256 + tid;
    g2l16(src + s * 4, (char*)wsm + s * 16);
  }
  __syncthreads();

  unsigned short* base = (unsigned short*)wb + (size_t)net * 589824;
#pragma unroll
  for (int it = 0; it < 5; ++it) {
    int c = it * 256 + tid;          // out chunk 0..1151 (tap-fastest)
    if (c < 1152) {
      int cv = (c * 7282) >> 16;     // c / 9
      int tap = c - cv * 9;
      int co_l = cv >> 5;
      int ci0 = (cv & 31) << 3;
      int dbase = co_l * 2304 + ci0 * 9 + tap;
      bf16x8 v;
#pragma unroll
      for (int e = 0; e < 8; ++e) v[e] = (short)f2bf(wsm[dbase + e * 9]);
      unsigned short* dst =
          base + ((size_t)(tap * 256 + cog * 4 + co_l) * 256 + ci0);
      *(bf16x8*)dst = v;
    }
  }
}

// ---------------------------------------------------------------------------
// Kernel 2: BN+ReLU + NCHW -> per-region NHWC bf16, block = (reg, b).
// (unchanged from round 2)
// ---------------------------------------------------------------------------
__global__ void bnrelu_kernel(const float* __restrict__ x,
                              const float* __restrict__ gamma,
                              const float* __restrict__ beta,
                              const float* __restrict__ mean,
                              const float* __restrict__ var,
                              __hip_bfloat16* __restrict__ hh) {
  const int blk = blockIdx.x;
  const int reg = blk >> 4, b = blk & 15;
  const int gi = reg >> 3, gj = reg & 7;
  const int net = gj * (gi + 1);
  const int tid = threadIdx.x;

  __shared__ float sc[256], sh[256];
  __shared__ __align__(16) unsigned short tile[64 * 256];  // 32 KB

  {
    float g = gamma[net * 256 + tid];
    float bt = beta[net * 256 + tid];
    float m = mean[net * 256 + tid];
    float v = var[net * 256 + tid];
    float s = g * rsqrtf(v + 1e-5f);
    sc[tid] = s;
    sh[tid] = bt - m * s;
  }
  __syncthreads();

  const float* xb = x + (size_t)b * 1048576 + (gi * 8) * 64 + gj * 8;
  const int px = tid & 63, cw = tid >> 6;
  const int yy = px >> 3, xx = px & 7;

#pragma unroll
  for (int j = 0; j < 8; ++j) {
    const int chunk = cw * 8 + j;
    const int c0 = chunk * 8;
    bf16x8 v;
#pragma unroll
    for (int e = 0; e < 8; ++e) {
      int c = c0 + e;
      float tv = xb[(size_t)c * 4096 + yy * 64 + xx];
      tv = fmaxf(tv * sc[c] + sh[c], 0.f);
      v[e] = (short)f2bf(tv);
    }
    int phys = (chunk + px) & 31;
    *(bf16x8*)&tile[px * 256 + phys * 8] = v;
  }
  __syncthreads();

  unsigned short* hb = (unsigned short*)(hh + (size_t)(reg * 16 + b) * 16384);
#pragma unroll
  for (int k = 0; k < 8; ++k) {
    int ck = k * 256 + tid;
    int p = ck >> 5, cl = ck & 31;
    int phys = (cl + p) & 31;
    bf16x8 v = *(const bf16x8*)&tile[p * 256 + phys * 8];
    *(bf16x8*)(hb + p * 256 + cl * 8) = v;
  }
}

// ---------------------------------------------------------------------------
// Kernel 3: implicit-GEMM conv, 128x128 wave tile (8x8 frags, 256 acc VGPR).
// Block = (r, mq): M=256 (batches mq*4..+3, 64 px each), N=256, grid 256 ->
// 1 block/CU, 1 wave/SIMD. A chunk (256row x 64ci = 32KB) staged per cc,
// single-buffered, row-rotate swizzle. B chunk (256co x 32ci = 16KB) staged
// per (cc32,tap) into 2x16KB double buffer; prefetch issued AFTER the
// barrier so its vmcnt drain lands after ~1240 cyc of MFMA. One barrier per
// chunk; 64 MFMA / wave between barriers. Halo: wrapped-row read + cndmask.
// ---------------------------------------------------------------------------
__global__ __launch_bounds__(256, 1) void conv_kernel(
    const __hip_bfloat16* __restrict__ hh,
    const __hip_bfloat16* __restrict__ wb,
    const float* __restrict__ xin,
    const float* __restrict__ cbias,
    float* __restrict__ outp) {
  __shared__ __align__(16) char sA[32768];  // 256 rows x 128B
  __shared__ __align__(16) char sB[32768];  // 2 x (256 co x 64B)

  const int bx = blockIdx.x;
  const int r = bx >> 2;
  const int mq = bx & 3;
  const int gi = r >> 3, gj = r & 7;
  const int net = gj * (gi + 1);

  const int tid = threadIdx.x;
  const int lane = tid & 63;
  const int wv = tid >> 6;
  const int wm = (wv & 1) * 128;
  const int wn = (wv >> 1) * 128;
  const int ln = lane & 15;
  const int q = lane >> 4;

  const unsigned short* hb =
      (const unsigned short*)hh + (size_t)(r * 16 + mq * 4) * 16384;
  const unsigned short* wbase = (const unsigned short*)wb + (size_t)net * 589824;

  // --- per-lane constants ---
  const int pxw = ln & 7;  // m&7, uniform across mf
  int pyb[8], rowb[8];
#pragma unroll
  for (int mf = 0; mf < 8; ++mf) {
    int m = wm + mf * 16 + ln;
    pyb[mf] = (m >> 3) & 7;
    rowb[mf] = m & 0xC0;  // b_loc*64
  }
  int boff[8];
#pragma unroll
  for (int nf = 0; nf < 8; ++nf) {
    int row = wn + nf * 16 + ln;
    boff[nf] = row * 64 + ((q + row) & 3) * 16;
  }

  f32x4 acc[8][8];
#pragma unroll
  for (int mf = 0; mf < 8; ++mf)
#pragma unroll
    for (int nf = 0; nf < 8; ++nf) acc[mf][nf] = (f32x4){0.f, 0.f, 0.f, 0.f};

  const bf16x8 zero8 = {0, 0, 0, 0, 0, 0, 0, 0};

  // --- staging helpers ---
  auto stageA = [&](int cc) {
#pragma unroll
    for (int p = 0; p < 8; ++p) {
      int s = p * 256 + tid;
      int row = s >> 3;
      int lg = ((s & 7) - row) & 7;  // logical chunk stored at phys s&7
      g2l16(hb + (row >> 6) * 16384 + (row & 63) * 256 + cc * 64 + lg * 8,
            sA + s * 16);
    }
  };
  auto stageB = [&](int cc32, int tap, int buf) {
#pragma unroll
    for (int p = 0; p < 4; ++p) {
      int s = p * 256 + tid;
      int row = s >> 2;
      int lg = ((s & 3) - row) & 3;
      g2l16(wbase + (size_t)tap * 65536 + row * 256 + cc32 * 32 + lg * 8,
            sB + buf * 16384 + s * 16);
    }
  };

  stageA(0);
  stageB(0, 0, 0);
  __syncthreads();

  int j = 0;  // global chunk counter 0..71
#pragma unroll 1
  for (int cc = 0; cc < 4; ++cc) {
#pragma unroll 1
    for (int t = 0; t < 18; ++t, ++j) {
      // prefetch next B chunk into the other buffer (post-barrier issue)
      int jn = j + 1;
      if (jn < 72) {
        int ccn = (jn * 3641) >> 16;  // jn / 18
        int tn = jn - ccn * 18;
        stageB(ccn * 2 + (tn & 1), tn >> 1, jn & 1);
      }
      const int tap = t >> 1, h = t & 1;
      const int tp3 = (tap * 11) >> 5;  // tap / 3
      const int dy = tp3 - 1, dx = tap - tp3 * 3 - 1;
      const char* bbuf = sB + (j & 1) * 16384;

      bf16x8 bfr[8];
#pragma unroll
      for (int nf = 0; nf < 8; ++nf)
        bfr[nf] = *(const bf16x8*)(bbuf + boff[nf]);

#pragma unroll
      for (int mf = 0; mf < 8; ++mf) {
        int sy = pyb[mf] + dy, sx = pxw + dx;
        bool ok = ((unsigned)sy < 8u) & ((unsigned)sx < 8u);
        int row = rowb[mf] | ((sy & 7) << 3) | (sx & 7);
        int ph = (h * 4 + q + row) & 7;
        bf16x8 a = *(const bf16x8*)(sA + row * 128 + ph * 16);
        a = ok ? a : zero8;
#pragma unroll
        for (int nf = 0; nf < 8; ++nf)
          acc[mf][nf] = __builtin_amdgcn_mfma_f32_16x16x32_bf16(
              a, bfr[nf], acc[mf][nf], 0, 0, 0);
      }
      __syncthreads();
      if (t == 17 && cc < 3) {
        stageA(cc + 1);
        __syncthreads();
      }
    }
  }

  // Epilogue: D col = lane&15 (n), row = q*4+reg (m): 4 consecutive x-pixels
  // per lane -> aligned float4 residual load + store.
#pragma unroll
  for (int nf = 0; nf < 8; ++nf) {
    const int n = wn + nf * 16 + ln;
    const float cb = cbias[net * 256 + n];
#pragma unroll
    for (int mf = 0; mf < 8; ++mf) {
      int mloc = wm + mf * 16 + q * 4;
      int b = mq * 4 + (mloc >> 6);
      int px = mloc & 63;
      int yy = px >> 3, x0 = px & 7;
      size_t off =
          (((size_t)b * 256 + n) * 64 + (gi * 8 + yy)) * 64 + (gj * 8 + x0);
      f32x4 res = *(const f32x4*)(xin + off);
      f32x4 o = acc[mf][nf];
      o = o + res;
      o = o + cb;
      *(f32x4*)(outp + off) = o;
    }
  }
}

// ---------------------------------------------------------------------------
extern "C" void kernel_launch(void* const* d_in, const int* in_sizes, int n_in,
                              void* d_out, int out_size, void* d_ws,
                              size_t ws_size, hipStream_t stream) {
  const float* x      = (const float*)d_in[0];
  const float* gamma  = (const float*)d_in[1];
  const float* beta   = (const float*)d_in[2];
  const float* mean   = (const float*)d_in[3];
  const float* var    = (const float*)d_in[4];
  const float* conv_w = (const float*)d_in[5];
  const float* conv_b = (const float*)d_in[6];
  float* out = (float*)d_out;

  __hip_bfloat16* wb = (__hip_bfloat16*)d_ws;                      // 75497472 B
  __hip_bfloat16* hh = (__hip_bfloat16*)((char*)d_ws + 75497472);  // 33554432 B

  wtrans_kernel<<<dim3(64, 64), 256, 0, stream>>>(conv_w, wb);
  bnrelu_kernel<<<1024, 256, 0, stream>>>(x, gamma, beta, mean, var, hh);
  conv_kernel<<<256, 256, 0, stream>>>(hh, wb, x, conv_b, out);
}